// Round 6
// baseline (251.385 us; speedup 1.0000x reference)
//
#include <hip/hip_runtime.h>
#include <stdint.h>

typedef int int32x4 __attribute__((ext_vector_type(4)));

#define HW_        3136          // 56*56
#define CHW_       802816        // 256*3136
#define HP_        58
#define WP_        58
#define PLANE_PIX  107648ull     // 32*58*58 pixels per 16-channel plane
#define PLANE_B    (PLANE_PIX*16)        // 1,722,368 B
#define QXP_BYTES  (16ull*PLANE_B)       // 27,557,888 B : [cq][b][hp][wp][16]
#define QWT_BYTES  (9ull*16*256*16)      // 589,824  B : [kk][cq][o][16]

__device__ __forceinline__ signed char quant8(float v, float s) {
    float t = v * s;
    t = fmaxf(t, -128.0f);                 // clip FIRST (round(clip(...)))
    t = fminf(t, 127.0f);
    return (signed char)(int)rintf(t);     // half-to-even == jnp.round
}

// ---------------- fused prep: quant_x + row-halo (+ quant_w on blocks >=1792) ----------------
__global__ __launch_bounds__(256) void prep_kernel(
    const float* __restrict__ x, const float* __restrict__ sx,
    const float* __restrict__ wgt, const float* __restrict__ sw,
    signed char* __restrict__ qxp2, signed char* __restrict__ qwT2)
{
    __shared__ __align__(16) signed char lw[9*272];
    const int tid = threadIdx.x;
    const int blk = blockIdx.x;

    if (blk >= 1792) {                     // ---- quant_w: o = blk-1792 ----
        const int o = blk - 1792;
        const float s = sw[o];
        const float* wp = wgt + ((size_t)o*256 + tid)*9;
        #pragma unroll
        for (int kk = 0; kk < 9; ++kk)
            lw[kk*272 + tid] = quant8(wp[kk], s);
        __syncthreads();
        if (tid < 144) {
            int kk = tid / 16, cq = tid - kk*16;
            int32x4 v = *(const int32x4*)&lw[kk*272 + cq*16];
            *(int32x4*)(qwT2 + ((size_t)(kk*16 + cq)*256 + o)*16) = v;
        }
        return;
    }

    // ---- quant_x for (b,h) = blk ----
    const int b = blk / 56, h = blk % 56;
    const float s = sx[0];
    if (tid < 224) {
        const int w  = tid % 56;
        const int cg = tid / 56;              // 0..3 -> cq = cg*4+k
        const size_t xrow = (size_t)b*CHW_ + (size_t)h*56 + w;
        const size_t pb = ((size_t)(b*HP_ + h + 1)*WP_ + 1 + w)*16;
        #pragma unroll
        for (int k = 0; k < 4; ++k) {
            const int cq = cg*4 + k;
            const float* xp = x + xrow + (size_t)(cq*16)*HW_;
            int pk[4];
            #pragma unroll
            for (int g = 0; g < 4; ++g) {
                int b0 = (unsigned char)quant8(xp[(size_t)(4*g+0)*HW_], s);
                int b1 = (unsigned char)quant8(xp[(size_t)(4*g+1)*HW_], s);
                int b2 = (unsigned char)quant8(xp[(size_t)(4*g+2)*HW_], s);
                int b3 = (unsigned char)quant8(xp[(size_t)(4*g+3)*HW_], s);
                pk[g] = b0 | (b1 << 8) | (b2 << 16) | (b3 << 24);
            }
            *(int32x4*)(qxp2 + (size_t)cq*PLANE_B + pb) = (int32x4){pk[0],pk[1],pk[2],pk[3]};
        }
    } else {
        // w-halo of this padded row: w = 0 and 57, all 16 cq
        int t2 = tid - 224;                   // 0..31
        int cq = t2 >> 1, wp = (t2 & 1) * (WP_-1);
        const size_t rowpix = (size_t)(b*HP_ + h + 1)*WP_;
        *(int32x4*)(qxp2 + ((size_t)cq*PLANE_PIX + rowpix + wp)*16) = (int32x4){0,0,0,0};
    }
    if (h == 0) {
        // row-halo: zero padded rows hp=0 and hp=57 for this b (all cq)
        for (int t = tid; t < 16*2*58; t += 256) {
            int cq = t / 116;
            int r  = t - cq*116;
            int hp = (r / 58) * (HP_-1);
            int wp = r % 58;
            *(int32x4*)(qxp2 + ((size_t)cq*PLANE_PIX + (size_t)(b*HP_+hp)*WP_ + wp)*16)
                = (int32x4){0,0,0,0};
        }
    }
}

// ---------------- int8 implicit-GEMM conv, kw-tap-reuse supersteps ----------------
// 12 supersteps = (kh 0..2) x (cq-group 0..3). Per superstep: stage ONE
// contiguous 256-slot padded span per chunk, then 3 kw-taps x 16 MFMA = 48
// MFMA per barrier. B triple-buffered (3 x 16KB), staged 2 ss ahead; A direct
// global->reg one burst ahead (ping-pong); B-fragments ds_read one burst
// ahead (bU/bN ping-pong) so LDS latency hides under the prior MFMA burst.
// NO intra-ss sched_barriers (round-5 lesson: order-pinning defeated the
// scheduler; the per-tap lgkmcnt(0) stall was ~40% of the wall).
__device__ __forceinline__ void load16_lds(const void* g, void* l) {
    __builtin_amdgcn_global_load_lds(
        (const unsigned int*)g,
        reinterpret_cast<__attribute__((address_space(3))) unsigned int*>(
            reinterpret_cast<uintptr_t>(l)),
        16, 0, 0);
}

// kh = st>>2, g = st&3
// stage chunk wv for superstep st: 4 x 1KB contiguous into buf[st%3].
// LDS dest is WAVE-UNIFORM base (HW adds lane*16); global src is per-lane.
#define STAGEB(st) {                                                          \
    const signed char* bG_ = qxp2                                             \
        + (size_t)(((st) & 3)*4 + wv)*PLANE_B                                 \
        + (base0 + (size_t)((st) >> 2)*WP_)*16 + (size_t)lane*16;             \
    signed char* dst_ = smem + ((st)%3)*16384 + wv*4096;                      \
    load16_lds(bG_ +    0, dst_ +    0);                                      \
    load16_lds(bG_ + 1024, dst_ + 1024);                                      \
    load16_lds(bG_ + 2048, dst_ + 2048);                                      \
    load16_lds(bG_ + 3072, dst_ + 3072);                                      \
}

// A fragment for (superstep nst, tap nkw) -> AF[0..3]
#define LOADA(nst, nkw, AF) {                                                 \
    const signed char* aG_ = aBase + (size_t)((((nst) >> 2)*3 + (nkw))*65536  \
                           + ((nst) & 3)*16384);                              \
    AF[0] = *(const int32x4*)(aG_ +   0);                                     \
    AF[1] = *(const int32x4*)(aG_ + 256);                                     \
    AF[2] = *(const int32x4*)(aG_ + 512);                                     \
    AF[3] = *(const int32x4*)(aG_ + 768);                                     \
}

// B fragments for (superstep st, tap kw) -> BF[0..3]  (plain loads: the
// compiler inserts exact lgkmcnt and is free to hoist under prior MFMA)
#define READB(st, kw, BF) {                                                   \
    _Pragma("unroll")                                                         \
    for (int t = 0; t < 4; ++t)                                               \
        BF[t] = *(const int32x4*)&smem[rA[t] + ((st)%3)*16384 + (kw)*16];     \
}

#define BURST(AC, BF) {                                                       \
    __builtin_amdgcn_s_setprio(1);                                            \
    _Pragma("unroll")                                                         \
    for (int mt = 0; mt < 4; ++mt)                                            \
        _Pragma("unroll")                                                     \
        for (int nt = 0; nt < 4; ++nt)                                        \
            acc[mt][nt] = __builtin_amdgcn_mfma_i32_16x16x64_i8(              \
                AC[mt], BF[nt], acc[mt][nt], 0, 0, 0);                        \
    __builtin_amdgcn_s_setprio(0);                                            \
}

// superstep. vmcnt(8) at top provably drains S(st) under any intra-region
// reorder (worst-case 20 in flight, 8 newest = A(st+1,0)+S(st+2)); compiler
// register-dep waits cover the A chain. ONE sched_barrier, right after the
// barrier (blocks ds_read hoisting into the still-being-staged region).
#define SS(st, X, Y) {                                                        \
    asm volatile("s_waitcnt vmcnt(8)");                                       \
    __builtin_amdgcn_s_barrier();                                             \
    __builtin_amdgcn_sched_barrier(0);                                        \
    READB(st, 0, bU);                                                         \
    LOADA(st, 1, Y);                                                          \
    READB(st, 1, bN);                                                         \
    BURST(X, bU);                 /* A(st,0) x bf(kw0) */                     \
    LOADA(st, 2, X);                                                          \
    READB(st, 2, bU);                                                         \
    if ((st) + 2 < 12) STAGEB((st) + 2);                                      \
    BURST(Y, bN);                 /* A(st,1) x bf(kw1) */                     \
    if ((st) + 1 < 12) LOADA((st) + 1, 0, Y);                                 \
    BURST(X, bU);                 /* A(st,2) x bf(kw2) */                     \
}

__global__ __launch_bounds__(256, 3) void conv_kernel(
    const signed char* __restrict__ qxp2, const signed char* __restrict__ qwT2,
    const float* __restrict__ sw, const float* __restrict__ bias,
    const float* __restrict__ sx, float* __restrict__ out)
{
    // B triple buffer: 3 x (4 chunks x 4096 B) = 49152.
    // epilogue aliases (ONLY after the post-K-loop __syncthreads rendezvous):
    // lt[64][132]f (33792 B) + invS/biasS at 33792/34304.
    __shared__ __align__(16) signed char smem[49152];

    const int tid  = threadIdx.x;
    const int wv   = tid >> 6;
    const int lane = tid & 63;
    const int quad = lane >> 4;
    const int l15  = lane & 15;

    // XCD-bijective swizzle (1568 = 8*196); o-tile pair adjacent -> L2 reuse.
    const int bid = blockIdx.x;
    const int swz = (bid & 7) * 196 + (bid >> 3);
    const int s0  = (swz >> 1) * 128;   // spatial tile
    const int o0  = (swz & 1) * 128;    // out-channel tile

    const int wo = (wv & 1) << 6;            // o half of wave tile
    const int wn = (wv >> 1) << 6;           // spatial half

    // tile-base padded slot (first pixel of tile, kh=0)
    const unsigned tb = (unsigned)s0 / HW_;
    const unsigned ttr = (unsigned)s0 - tb*HW_;
    const unsigned th = ttr / 56, twc = ttr - th*56;
    const size_t base0 = (size_t)(tb*HP_ + th)*WP_ + twc;

    // per-lane LDS read bases: chunk=quad, slot-delta of the lane's pixel for
    // fragment t (kh-independent; kw added as 16B immediate)
    int rA[4];
    #pragma unroll
    for (int t = 0; t < 4; ++t) {
        unsigned sp = (unsigned)(s0 + wn + t*16 + l15);
        unsigned b = sp / HW_, r = sp - b*HW_;
        unsigned h = r / 56,   w = r - h*56;
        unsigned slot = (b*HP_ + h)*WP_ + w;
        rA[t] = quad*4096 + (int)(slot - (unsigned)base0)*16;
    }

    const signed char* aBase = qwT2 + (size_t)quad*4096 + (size_t)(o0 + wo + l15)*16;

    int32x4 acc[4][4];
    #pragma unroll
    for (int i = 0; i < 4; ++i)
        #pragma unroll
        for (int j = 0; j < 4; ++j)
            acc[i][j] = (int32x4){0,0,0,0};

    int32x4 aP[4], aQ[4];
    int32x4 bU[4], bN[4];

    // prologue: B(0), B(1) staged (8 loads), A(0,0) (4 loads) -> 12 in flight
    STAGEB(0);
    STAGEB(1);
    __builtin_amdgcn_sched_barrier(0);
    LOADA(0, 0, aP);
    __builtin_amdgcn_sched_barrier(0);

    SS(0,  aP, aQ)  SS(1,  aQ, aP)  SS(2,  aP, aQ)  SS(3,  aQ, aP)
    SS(4,  aP, aQ)  SS(5,  aQ, aP)  SS(6,  aP, aQ)  SS(7,  aQ, aP)
    SS(8,  aP, aQ)  SS(9,  aQ, aP)  SS(10, aP, aQ)  SS(11, aQ, aP)

    // rendezvous BEFORE any epilogue write to smem: SS(11) reads buf2, and
    // invS/biasS (33792..34816) alias buf2.
    __syncthreads();

    // ---- epilogue: LDS transpose -> full-line float4 stores ----
    float* lt    = (float*)smem;                   // [64][132] floats = 33792 B
    float* invS  = (float*)(smem + 33792);
    float* biasS = (float*)(smem + 34304);
    if (tid < 128) {
        float s = sw[o0 + tid];
        invS[tid]  = 1.0f / (s * sx[0]);
        biasS[tid] = bias[o0 + tid];
    }
    #pragma unroll
    for (int p = 0; p < 2; ++p) {
        __syncthreads();
        if ((wv & 1) == p) {
            #pragma unroll
            for (int mt = 0; mt < 4; ++mt)
                #pragma unroll
                for (int nt = 0; nt < 4; ++nt)
                    #pragma unroll
                    for (int r = 0; r < 4; ++r)
                        lt[(mt*16 + quad*4 + r)*132 + wn + nt*16 + l15]
                            = (float)acc[mt][nt][r];
        }
        __syncthreads();
        #pragma unroll
        for (int i = 0; i < 8; ++i) {
            int idx = i*256 + tid;                 // 2048 float4 chunks
            int o = idx >> 5;                      // 0..63
            int c = idx & 31;                      // sp/4 chunk
            float4 v = *(const float4*)&lt[o*132 + 4*c];
            int ol = p*64 + o;
            float is = invS[ol], bs = biasS[ol];
            unsigned sp = (unsigned)(s0 + 4*c);
            unsigned b  = sp / HW_;
            unsigned pos = sp - b*HW_;
            float4 wv4;
            wv4.x = fmaf(v.x, is, bs); wv4.y = fmaf(v.y, is, bs);
            wv4.z = fmaf(v.z, is, bs); wv4.w = fmaf(v.w, is, bs);
            *(float4*)(out + (size_t)b*CHW_ + (size_t)(o0 + ol)*HW_ + pos) = wv4;
        }
    }
}

extern "C" void kernel_launch(void* const* d_in, const int* in_sizes, int n_in,
                              void* d_out, int out_size, void* d_ws, size_t ws_size,
                              hipStream_t stream)
{
    (void)in_sizes; (void)n_in; (void)out_size; (void)ws_size;
    const float* x    = (const float*)d_in[0];
    const float* wgt  = (const float*)d_in[1];
    const float* bias = (const float*)d_in[2];
    const float* sw   = (const float*)d_in[3];
    const float* sx   = (const float*)d_in[4];
    float* out = (float*)d_out;

    signed char* qxp2 = (signed char*)d_ws;           // [cq][b][hp][wp][16]
    signed char* qwT2 = qxp2 + QXP_BYTES;             // [kk][cq][o][16]

    prep_kernel<<<2048, 256, 0, stream>>>(x, sx, wgt, sw, qxp2, qwT2);
    conv_kernel<<<1568, 256, 0, stream>>>(qxp2, qwT2, sw, bias, sx, out);
}